// Round 9
// baseline (898.814 us; speedup 1.0000x reference)
//
#include <hip/hip_runtime.h>
#include <hip/hip_bf16.h>
#include <stdint.h>

#define Bsz 4
#define Nn 4096
#define Dd 512
#define THETA 0.08f
#define STRIPE_CAP 16
#define LCAP 512

typedef unsigned short u16;
typedef __attribute__((ext_vector_type(8))) short bf16x8;
typedef __attribute__((ext_vector_type(4))) float f32x4;
typedef __attribute__((address_space(3))) uint32_t lds_as;
typedef __attribute__((address_space(1))) const uint32_t gbl_as;

__device__ __forceinline__ u16 bf16_of(float v) {
  __hip_bfloat16 h = __float2bfloat16(v);
  return __builtin_bit_cast(u16, h);
}
__device__ __forceinline__ float f_of_bf16(u16 u) {
  return __uint_as_float(((uint32_t)u) << 16);
}

// ---------------- K1: normalize + split bf16 hi/lo ----------------
__global__ __launch_bounds__(128) void prep_kernel(const float* __restrict__ x,
                                                   float* __restrict__ rinv,
                                                   u16* __restrict__ xh,
                                                   u16* __restrict__ xl) {
  int row = blockIdx.x;   // B*N rows
  int t = threadIdx.x;    // 128 threads, one float4 each
  const float4* xr = (const float4*)(x + (size_t)row * Dd);
  float4 v = xr[t];
  float s = v.x * v.x + v.y * v.y + v.z * v.z + v.w * v.w;
  for (int o = 32; o > 0; o >>= 1) s += __shfl_down(s, o, 64);
  __shared__ float ls[2];
  if ((t & 63) == 0) ls[t >> 6] = s;
  __syncthreads();
  float ri = 1.0f / fmaxf(sqrtf(ls[0] + ls[1]), 1e-12f);
  if (t == 0) rinv[row] = ri;
  float n0 = v.x * ri, n1 = v.y * ri, n2 = v.z * ri, n3 = v.w * ri;
  u16 h0 = bf16_of(n0), h1 = bf16_of(n1), h2 = bf16_of(n2), h3 = bf16_of(n3);
  u16 l0 = bf16_of(n0 - f_of_bf16(h0));
  u16 l1 = bf16_of(n1 - f_of_bf16(h1));
  u16 l2 = bf16_of(n2 - f_of_bf16(h2));
  u16 l3 = bf16_of(n3 - f_of_bf16(h3));
  uint2 hp, lp;
  hp.x = (uint32_t)h0 | ((uint32_t)h1 << 16);
  hp.y = (uint32_t)h2 | ((uint32_t)h3 << 16);
  lp.x = (uint32_t)l0 | ((uint32_t)l1 << 16);
  lp.y = (uint32_t)l2 | ((uint32_t)l3 << 16);
  *(uint2*)(xh + (size_t)row * Dd + t * 4) = hp;
  *(uint2*)(xl + (size_t)row * Dd + t * 4) = lp;
}

// ---------------- K2: symmetric split-bf16 MFMA GEMM -> striped candidate lists ----------------
// K-loop identical to rounds 6/7/8 (verified). Epilogue: candidates staged in the
// dead 32KB tile-LDS via LDS atomics, then PLAIN stores to exclusively-owned
// cand[row][stripe][16] cells. Zero global atomics. Per-stripe counts stored
// uncapped so overflow (P ~ 5e-6/cell) is detected and the row falls back.
__global__ __launch_bounds__(256) void gemm_sym(const u16* __restrict__ xh,
                                                const u16* __restrict__ xl,
                                                uint32_t* __restrict__ cnt2,
                                                uint2* __restrict__ cand) {
  __shared__ __align__(16) u16 lds[4 * 128 * 32];   // 32 KB; reused as stage
  __shared__ int lcnt[256];
  int b = blockIdx.y;
  int p = blockIdx.x;             // 0..527 upper-triangle tile pairs (T=32)
  const int T = Nn / 128;
  int ti = 0;
  while (p >= T - ti) { p -= T - ti; ti++; }
  int tj = ti + p;
  int ri0 = ti * 128, rj0 = tj * 128;
  int tid = threadIdx.x, wid = tid >> 6, lane = tid & 63;
  int wr = (wid >> 1) * 64, wc = (wid & 1) * 64;   // wave's 64x64 quadrant
  int frow = lane & 15, kg = lane >> 4;

  // staging role: wave wid stages tile wid (0=Ah,1=Al,2=Bh,3=Bl)
  const u16* src = (wid & 1) ? xl : xh;
  int rbase = (wid >> 1) ? rj0 : ri0;
  const u16* sb = src + ((size_t)b * Nn + rbase) * Dd;
  u16* tb = &lds[wid * 4096];
  int lrow = lane >> 2;
  int g = lane & 3;

  f32x4 acc[4][4];
#pragma unroll
  for (int mt = 0; mt < 4; mt++)
#pragma unroll
    for (int nt = 0; nt < 4; nt++) acc[mt][nt] = (f32x4){0.f, 0.f, 0.f, 0.f};

  for (int k0 = 0; k0 < Dd; k0 += 32) {
    __syncthreads();
#pragma unroll
    for (int i = 0; i < 8; i++) {
      int r = i * 16 + lrow;
      int gs = g ^ ((r >> 1) & 3);
      const u16* gp = sb + (size_t)r * Dd + k0 + gs * 8;
      __builtin_amdgcn_global_load_lds((gbl_as*)gp, (lds_as*)(tb + i * 512), 16, 0, 0);
    }
    __syncthreads();

    bf16x8 bhf[4], blf[4];
#pragma unroll
    for (int nt = 0; nt < 4; nt++) {
      int rB = wc + nt * 16 + frow;
      int offB = rB * 32 + ((kg ^ ((rB >> 1) & 3)) * 8);
      bhf[nt] = *(const bf16x8*)&lds[8192 + offB];
      blf[nt] = *(const bf16x8*)&lds[12288 + offB];
    }
#pragma unroll
    for (int mt = 0; mt < 4; mt++) {
      int rA = wr + mt * 16 + frow;
      int offA = rA * 32 + ((kg ^ ((rA >> 1) & 3)) * 8);
      bf16x8 ah = *(const bf16x8*)&lds[offA];
      bf16x8 al = *(const bf16x8*)&lds[4096 + offA];
#pragma unroll
      for (int nt = 0; nt < 4; nt++) {
        acc[mt][nt] = __builtin_amdgcn_mfma_f32_16x16x32_bf16(ah, bhf[nt], acc[mt][nt], 0, 0, 0);
        acc[mt][nt] = __builtin_amdgcn_mfma_f32_16x16x32_bf16(ah, blf[nt], acc[mt][nt], 0, 0, 0);
        acc[mt][nt] = __builtin_amdgcn_mfma_f32_16x16x32_bf16(al, bhf[nt], acc[mt][nt], 0, 0, 0);
      }
    }
  }

  // ---- epilogue: filter > THETA into LDS stage, then plain global stores ----
  lcnt[tid] = 0;
  __syncthreads();          // tiles fully consumed AND counters zeroed
  uint2* stage = (uint2*)lds;   // [256][STRIPE_CAP]
#pragma unroll
  for (int mt = 0; mt < 4; mt++) {
    int rl0 = wr + mt * 16 + (lane >> 4) * 4;   // local row base 0..127
#pragma unroll
    for (int nt = 0; nt < 4; nt++) {
      int cl = wc + nt * 16 + frow;             // local col 0..127
      float vv[4] = {acc[mt][nt].x, acc[mt][nt].y, acc[mt][nt].z, acc[mt][nt].w};
#pragma unroll
      for (int c = 0; c < 4; c++) {
        float vb = f_of_bf16(bf16_of(vv[c]));   // bf16-rounded sim (verified semantics)
        if (vb > THETA) {
          int slot = atomicAdd(&lcnt[rl0 + c], 1);
          if (slot < STRIPE_CAP)
            stage[(rl0 + c) * STRIPE_CAP + slot] = make_uint2(__float_as_uint(vb), (uint32_t)(rj0 + cl));
          if (ti != tj) {
            int s2 = atomicAdd(&lcnt[128 + cl], 1);
            if (s2 < STRIPE_CAP)
              stage[(128 + cl) * STRIPE_CAP + s2] = make_uint2(__float_as_uint(vb), (uint32_t)(ri0 + rl0 + c));
          }
        }
      }
    }
  }
  __syncthreads();
  if (tid < 128) {
    int rg = b * Nn + ri0 + tid;
    int cv = lcnt[tid];
    cnt2[(size_t)rg * 32 + tj] = (uint32_t)cv;   // uncapped: overflow detectable
    int m = cv < STRIPE_CAP ? cv : STRIPE_CAP;
    for (int s = 0; s < m; s++)
      cand[((size_t)rg * 32 + tj) * STRIPE_CAP + s] = stage[tid * STRIPE_CAP + s];
  } else if (ti != tj) {
    int cl = tid - 128;
    int rg = b * Nn + rj0 + cl;
    int cv = lcnt[128 + cl];
    cnt2[(size_t)rg * 32 + ti] = (uint32_t)cv;
    int m = cv < STRIPE_CAP ? cv : STRIPE_CAP;
    for (int s = 0; s < m; s++)
      cand[((size_t)rg * 32 + ti) * STRIPE_CAP + s] = stage[(128 + cl) * STRIPE_CAP + s];
  }
}

// ---------------- K3: zero the output ----------------
__global__ __launch_bounds__(256) void zero_kernel(float4* __restrict__ o) {
  size_t i = (size_t)blockIdx.x * 256 + threadIdx.x;   // 4096 blocks
#pragma unroll
  for (int k = 0; k < 16; k++)
    o[i + (size_t)k * 1048576] = (float4){0.f, 0.f, 0.f, 0.f};
}

// ---------------- K4: gather stripes + rank + band refinement + scatter ----------------
__global__ __launch_bounds__(256) void select_kernel(const uint32_t* __restrict__ cnt2,
                                                     const uint2* __restrict__ cand,
                                                     const float* __restrict__ x,
                                                     const float* __restrict__ rinv,
                                                     float* __restrict__ out) {
  int row = blockIdx.x;   // global row in [0, B*N)
  int t = threadIdx.x;    // 256
  __shared__ float lv[LCAP];
  __shared__ int li[LCAP];
  __shared__ int scnt[32], soff[33];
  __shared__ int ovf;
  __shared__ float keepVal[40];
  __shared__ int keepIdx[40];
  __shared__ float bandLv[96], bandV[96];
  __shared__ int bandIdx[96];
  __shared__ int keepCnt, bandCnt, listCnt;
  __shared__ float sS;

  int bb = row >> 12;
  int rl = row & (Nn - 1);
  const float* xn = x + (size_t)row * Dd;
  const float* xbb = x + (((size_t)bb) << 12) * Dd;
  const float* rv = rinv + (bb << 12);
  float ra = rinv[row];

  if (t == 0) ovf = 0;
  __syncthreads();
  if (t < 32) {
    int c = (int)cnt2[(size_t)row * 32 + t];
    scnt[t] = c;
    if (c > STRIPE_CAP) ovf = 1;
  }
  __syncthreads();
  if (t == 0) {
    int a = 0;
    for (int i = 0; i < 32; i++) {
      soff[i] = a;
      int c = scnt[i]; if (c > STRIPE_CAP) c = STRIPE_CAP;
      a += c;
    }
    soff[32] = a;
  }
  __syncthreads();
  int L = soff[32];
  bool fb = (ovf != 0) || (L < 36);
  float S = 0.f, eb = 0.f;

  if (!fb) {
    if (t < 32) {
      int c = scnt[t];   // <= STRIPE_CAP here (no ovf)
      int o = soff[t];
      const uint2* cp = &cand[((size_t)row * 32 + t) * STRIPE_CAP];
      for (int s = 0; s < c; s++) {
        uint2 u = cp[s];
        lv[o + s] = __uint_as_float(u.x);
        li[o + s] = (int)u.y;
      }
    }
    __syncthreads();
    // exact rank-31 (value desc, index asc) = 32nd largest
    for (int e = t; e < L; e += 256) {
      float ve = lv[e]; int ie = li[e];
      int rank = 0;
      for (int q = 0; q < L; q++) {
        float vq = lv[q]; int iq = li[q];
        rank += ((vq > ve) || (vq == ve && iq < ie)) ? 1 : 0;
      }
      if (rank == 31) sS = ve;
    }
    __syncthreads();
    S = sS;
    eb = fmaxf(3e-4f, fabsf(S) * 4e-3f);
    if (S - eb <= THETA) fb = true;   // band reaches below filter: bail out
  }

  if (fb) {
    // safety path (~2-3 rows): full-row fp32 recompute, exact top-32.
    // Filter at THETA (expected ~145 candidates << LCAP=512; v32 >= 0.095 > THETA
    // over all rows, 9 sigma). R8 BUG WAS HERE: 0.05 filter overflowed LCAP.
    if (t == 0) { listCnt = 0; keepCnt = 0; }
    __syncthreads();
    for (int c = t; c < Nn; c += 256) {
      const float* xm = xbb + (size_t)c * Dd;
      float dot = 0.f;
      for (int k = 0; k < Dd; k += 4) {
        float4 a4 = *(const float4*)(xn + k);
        float4 b4 = *(const float4*)(xm + k);
        dot = fmaf(a4.x, b4.x, dot);
        dot = fmaf(a4.y, b4.y, dot);
        dot = fmaf(a4.z, b4.z, dot);
        dot = fmaf(a4.w, b4.w, dot);
      }
      float v = (dot * ra) * rv[c];
      if (v > THETA) {
        int slot = atomicAdd(&listCnt, 1);
        if (slot < LCAP) { lv[slot] = v; li[slot] = c; }
      }
    }
    __syncthreads();
    int Lf = listCnt; if (Lf > LCAP) Lf = LCAP;
    for (int e = t; e < Lf; e += 256) {
      float ve = lv[e]; int ie = li[e];
      int rank = 0;
      for (int q = 0; q < Lf; q++) {
        float vq = lv[q]; int iq = li[q];
        rank += ((vq > ve) || (vq == ve && iq < ie)) ? 1 : 0;
      }
      if (rank < 32) {
        int k = atomicAdd(&keepCnt, 1);
        keepIdx[k] = ie; keepVal[k] = ve;
      }
    }
    __syncthreads();
  } else {
    float hiT = S + eb, loT = S - eb;
    if (t == 0) { keepCnt = 0; bandCnt = 0; }
    __syncthreads();
    for (int s = t; s < L; s += 256) {
      float v = lv[s];
      if (v > hiT) {
        int k = atomicAdd(&keepCnt, 1);
        keepIdx[k] = li[s]; keepVal[k] = v;
      } else if (v >= loT) {
        int bs = atomicAdd(&bandCnt, 1);
        if (bs < 96) { bandIdx[bs] = li[s]; bandLv[bs] = v; }
      }
    }
    __syncthreads();
    int A = keepCnt;
    int BC = bandCnt; if (BC > 96) BC = 96;
    int need = 32 - A;
    bool heavy = (BC > need);
    if (heavy) {
      // resolve band order with the bitwise round-1 fp32 chain
      for (int s = t; s < BC; s += 256) {
        int m = bandIdx[s];
        const float* xm = xbb + (size_t)m * Dd;
        float dot = 0.f;
        for (int k = 0; k < Dd; k += 4) {
          float4 a4 = *(const float4*)(xn + k);
          float4 b4 = *(const float4*)(xm + k);
          dot = fmaf(a4.x, b4.x, dot);
          dot = fmaf(a4.y, b4.y, dot);
          dot = fmaf(a4.z, b4.z, dot);
          dot = fmaf(a4.w, b4.w, dot);
        }
        bandV[s] = (dot * ra) * rv[m];
      }
    }
    __syncthreads();
    if (t == 0) {
      if (!heavy) {
        for (int s = 0; s < BC; s++) { keepIdx[A + s] = bandIdx[s]; keepVal[A + s] = bandLv[s]; }
        keepCnt = A + BC;   // == 32 by rank invariant
      } else {
        int app = 0;
        for (int s = 0; s < need; s++) {
          float bv = -1e30f; int bidx = 0x7FFFFFFF, bs = -1;
          for (int q = 0; q < BC; q++) {
            int gi = bandIdx[q];
            if (gi < 0) continue;
            float v = bandV[q];
            if (v > bv || (v == bv && gi < bidx)) { bv = v; bidx = gi; bs = q; }
          }
          if (bs < 0) break;
          keepIdx[A + app] = bandIdx[bs]; keepVal[A + app] = bandLv[bs];
          bandIdx[bs] = -1; app++;
        }
        keepCnt = A + app;
      }
    }
    __syncthreads();
  }

  int KC = keepCnt;
  if (t < KC) {
    int m = keepIdx[t];
    float hv = 0.5f * keepVal[t];
    float* ob = out + (((size_t)bb) << 24);
    atomicAdd(ob + (size_t)rl * Nn + m, hv);
    atomicAdd(ob + (size_t)m * Nn + rl, hv);
  }
}

extern "C" void kernel_launch(void* const* d_in, const int* in_sizes, int n_in,
                              void* d_out, int out_size, void* d_ws, size_t ws_size,
                              hipStream_t stream) {
  const float* x = (const float*)d_in[0];
  float* out = (float*)d_out;
  // ws layout: rinv 64KB | cnt2 2MB | xh 16MB | xl 16MB | cand 64MB
  float* rinv = (float*)d_ws;
  uint32_t* cnt2 = (uint32_t*)((char*)d_ws + 65536);
  u16* xh = (u16*)((char*)d_ws + 65536 + 2097152);
  u16* xl = xh + (size_t)Bsz * Nn * Dd;
  uint2* cand = (uint2*)((char*)xl + (size_t)Bsz * Nn * Dd * sizeof(u16));

  prep_kernel<<<Bsz * Nn, 128, 0, stream>>>(x, rinv, xh, xl);
  dim3 g2(528, Bsz);
  gemm_sym<<<g2, 256, 0, stream>>>(xh, xl, cnt2, cand);
  zero_kernel<<<4096, 256, 0, stream>>>((float4*)out);
  select_kernel<<<Bsz * Nn, 256, 0, stream>>>(cnt2, cand, x, rinv, out);
}

// Round 11
// 689.011 us; speedup vs baseline: 1.3045x; 1.3045x over previous
//
#include <hip/hip_runtime.h>
#include <hip/hip_bf16.h>
#include <stdint.h>

#define Bsz 4
#define Nn 4096
#define Dd 512
#define THETA 0.08f

typedef unsigned short u16;
typedef __attribute__((ext_vector_type(8))) short bf16x8;
typedef __attribute__((ext_vector_type(4))) float f32x4;
typedef __attribute__((address_space(3))) uint32_t lds_as;
typedef __attribute__((address_space(1))) const uint32_t gbl_as;

__device__ __forceinline__ u16 bf16_of(float v) {
  __hip_bfloat16 h = __float2bfloat16(v);
  return __builtin_bit_cast(u16, h);
}
__device__ __forceinline__ float f_of_bf16(u16 u) {
  return __uint_as_float(((uint32_t)u) << 16);
}

// ---------------- K1: normalize + split bf16 hi/lo + zero output slice ----------------
__global__ __launch_bounds__(128) void prep_kernel(const float* __restrict__ x,
                                                   float* __restrict__ rinv,
                                                   u16* __restrict__ xh,
                                                   u16* __restrict__ xl,
                                                   float4* __restrict__ outz) {
  int row = blockIdx.x;   // B*N rows
  int t = threadIdx.x;    // 128 threads, one float4 each
  const float4* xr = (const float4*)(x + (size_t)row * Dd);
  float4 v = xr[t];
  float s = v.x * v.x + v.y * v.y + v.z * v.z + v.w * v.w;
  for (int o = 32; o > 0; o >>= 1) s += __shfl_down(s, o, 64);
  __shared__ float ls[2];
  if ((t & 63) == 0) ls[t >> 6] = s;
  __syncthreads();
  float ri = 1.0f / fmaxf(sqrtf(ls[0] + ls[1]), 1e-12f);
  if (t == 0) rinv[row] = ri;
  float n0 = v.x * ri, n1 = v.y * ri, n2 = v.z * ri, n3 = v.w * ri;
  u16 h0 = bf16_of(n0), h1 = bf16_of(n1), h2 = bf16_of(n2), h3 = bf16_of(n3);
  u16 l0 = bf16_of(n0 - f_of_bf16(h0));
  u16 l1 = bf16_of(n1 - f_of_bf16(h1));
  u16 l2 = bf16_of(n2 - f_of_bf16(h2));
  u16 l3 = bf16_of(n3 - f_of_bf16(h3));
  uint2 hp, lp;
  hp.x = (uint32_t)h0 | ((uint32_t)h1 << 16);
  hp.y = (uint32_t)h2 | ((uint32_t)h3 << 16);
  lp.x = (uint32_t)l0 | ((uint32_t)l1 << 16);
  lp.y = (uint32_t)l2 | ((uint32_t)l3 << 16);
  *(uint2*)(xh + (size_t)row * Dd + t * 4) = hp;
  *(uint2*)(xl + (size_t)row * Dd + t * 4) = lp;
  // zero this row's slice of the output (1024 float4 per block)
  float4 z4 = {0.f, 0.f, 0.f, 0.f};
  size_t zb = (size_t)row * 1024 + t;
#pragma unroll
  for (int k = 0; k < 8; k++) outz[zb + k * 128] = z4;
}

// ---------------- K2: symmetric split-bf16 MFMA GEMM -> bf16 sim matrix (R6 verbatim) ----------------
__global__ __launch_bounds__(256) void gemm_sym(const u16* __restrict__ xh,
                                                const u16* __restrict__ xl,
                                                u16* __restrict__ simb) {
  __shared__ __align__(16) u16 lds[4 * 128 * 32];   // 32 KB
  int b = blockIdx.y;
  int p = blockIdx.x;             // 0..527 upper-triangle tile pairs (T=32)
  const int T = Nn / 128;
  int ti = 0;
  while (p >= T - ti) { p -= T - ti; ti++; }
  int tj = ti + p;
  int ri0 = ti * 128, rj0 = tj * 128;
  int tid = threadIdx.x, wid = tid >> 6, lane = tid & 63;
  int wr = (wid >> 1) * 64, wc = (wid & 1) * 64;
  int frow = lane & 15, kg = lane >> 4;

  const u16* src = (wid & 1) ? xl : xh;
  int rbase = (wid >> 1) ? rj0 : ri0;
  const u16* sb = src + ((size_t)b * Nn + rbase) * Dd;
  u16* tb = &lds[wid * 4096];
  int lrow = lane >> 2;
  int g = lane & 3;

  f32x4 acc[4][4];
#pragma unroll
  for (int mt = 0; mt < 4; mt++)
#pragma unroll
    for (int nt = 0; nt < 4; nt++) acc[mt][nt] = (f32x4){0.f, 0.f, 0.f, 0.f};

  for (int k0 = 0; k0 < Dd; k0 += 32) {
    __syncthreads();
#pragma unroll
    for (int i = 0; i < 8; i++) {
      int r = i * 16 + lrow;
      int gs = g ^ ((r >> 1) & 3);
      const u16* gp = sb + (size_t)r * Dd + k0 + gs * 8;
      __builtin_amdgcn_global_load_lds((gbl_as*)gp, (lds_as*)(tb + i * 512), 16, 0, 0);
    }
    __syncthreads();

    bf16x8 bhf[4], blf[4];
#pragma unroll
    for (int nt = 0; nt < 4; nt++) {
      int rB = wc + nt * 16 + frow;
      int offB = rB * 32 + ((kg ^ ((rB >> 1) & 3)) * 8);
      bhf[nt] = *(const bf16x8*)&lds[8192 + offB];
      blf[nt] = *(const bf16x8*)&lds[12288 + offB];
    }
#pragma unroll
    for (int mt = 0; mt < 4; mt++) {
      int rA = wr + mt * 16 + frow;
      int offA = rA * 32 + ((kg ^ ((rA >> 1) & 3)) * 8);
      bf16x8 ah = *(const bf16x8*)&lds[offA];
      bf16x8 al = *(const bf16x8*)&lds[4096 + offA];
#pragma unroll
      for (int nt = 0; nt < 4; nt++) {
        acc[mt][nt] = __builtin_amdgcn_mfma_f32_16x16x32_bf16(ah, bhf[nt], acc[mt][nt], 0, 0, 0);
        acc[mt][nt] = __builtin_amdgcn_mfma_f32_16x16x32_bf16(ah, blf[nt], acc[mt][nt], 0, 0, 0);
        acc[mt][nt] = __builtin_amdgcn_mfma_f32_16x16x32_bf16(al, bhf[nt], acc[mt][nt], 0, 0, 0);
      }
    }
  }

  // epilogue: C/D layout col=lane&15, row=(lane>>4)*4+reg; write bf16 sim + mirror
  u16* ob = simb + (size_t)b * Nn * Nn;
#pragma unroll
  for (int mt = 0; mt < 4; mt++) {
    int rowg0 = ri0 + wr + mt * 16 + (lane >> 4) * 4;
#pragma unroll
    for (int nt = 0; nt < 4; nt++) {
      int colg = rj0 + wc + nt * 16 + frow;
      u16 u0 = bf16_of(acc[mt][nt].x);
      u16 u1 = bf16_of(acc[mt][nt].y);
      u16 u2 = bf16_of(acc[mt][nt].z);
      u16 u3 = bf16_of(acc[mt][nt].w);
      ob[(size_t)(rowg0 + 0) * Nn + colg] = u0;
      ob[(size_t)(rowg0 + 1) * Nn + colg] = u1;
      ob[(size_t)(rowg0 + 2) * Nn + colg] = u2;
      ob[(size_t)(rowg0 + 3) * Nn + colg] = u3;
      if (ti != tj) {
        uint2 m;
        m.x = (uint32_t)u0 | ((uint32_t)u1 << 16);
        m.y = (uint32_t)u2 | ((uint32_t)u3 << 16);
        *(uint2*)&ob[(size_t)colg * Nn + rowg0] = m;   // bitwise-identical mirror
      }
    }
  }
}

// ---------------- K3: wave-per-row select + scatter (64-thread workgroup) ----------------
// One wave per workgroup: all branches wave-uniform, every __syncthreads is a
// cheap single-wave barrier providing the LDS ordering guarantees.
__global__ __launch_bounds__(64) void select_kernel(const u16* __restrict__ simb,
                                                    const float* __restrict__ x,
                                                    const float* __restrict__ rinv,
                                                    float* __restrict__ out) {
  __shared__ uint2 cl[512];       // (fp32-of-bf16 val bits, idx)
  __shared__ float keepV[40];
  __shared__ int keepI[40];
  __shared__ uint2 bandU[96];
  __shared__ float bandRef[96];
  __shared__ int kcEnd;
  __shared__ int wcnt;

  int lane = threadIdx.x;
  int row = blockIdx.x;
  int bb = row >> 12;
  int rl = row & (Nn - 1);
  const float* xn = x + (size_t)row * Dd;
  const float* xbb = x + (((size_t)bb) << 12) * Dd;
  const float* rv = rinv + (bb << 12);
  float ra = rinv[row];

  // --- read sim row (coalesced uint4), ballot-compact >THETA into cl ---
  const uint4* srow = (const uint4*)(simb + (size_t)row * Nn);
  int L = 0;
  for (int i = 0; i < 8; i++) {
    uint4 u = srow[i * 64 + lane];
    uint32_t w[4] = {u.x, u.y, u.z, u.w};
    int base = (i * 64 + lane) * 8;
#pragma unroll
    for (int h = 0; h < 8; h++) {
      uint32_t bits = (h & 1) ? (w[h >> 1] & 0xFFFF0000u) : ((w[h >> 1] & 0xFFFFu) << 16);
      float v = __uint_as_float(bits);
      bool val = (v > THETA);
      unsigned long long bal = __ballot(val);
      int pos = L + (int)__popcll(bal & ((1ull << lane) - 1ull));
      if (val && pos < 512) cl[pos] = make_uint2(bits, (uint32_t)(base + h));
      L += (int)__popcll(bal);
    }
  }
  __syncthreads();

  bool fb = (L < 36) || (L > 512);
  float S = 0.f, eb = 0.f;
  float ve[8]; int ie[8]; int rk[8];

  if (!fb) {
#pragma unroll
    for (int j = 0; j < 8; j++) {
      int e = lane + 64 * j;
      if (e < L) { uint2 u = cl[e]; ve[j] = __uint_as_float(u.x); ie[j] = (int)u.y; rk[j] = 0; }
      else { ve[j] = 0.f; ie[j] = 0; rk[j] = 1 << 20; }
    }
    for (int q = 0; q < L; q++) {
      uint2 u = cl[q];
      float vq = __uint_as_float(u.x); int iq = (int)u.y;
#pragma unroll
      for (int j = 0; j < 8; j++)
        rk[j] += ((vq > ve[j]) || (vq == ve[j] && iq < ie[j])) ? 1 : 0;
    }
    float myS = 0.f; bool has = false;
#pragma unroll
    for (int j = 0; j < 8; j++) if (rk[j] == 31) { myS = ve[j]; has = true; }
    unsigned long long bal = __ballot(has);
    if (bal == 0ull) fb = true;           // defensive (cannot happen: L >= 36)
    else {
      int srcl = (int)__ffsll((long long)bal) - 1;
      S = __shfl(myS, srcl, 64);
      eb = fmaxf(3e-4f, fabsf(S) * 4e-3f);
      if (S - eb <= THETA) fb = true;     // band reaches below filter: bail out
    }
  }

  int KC = 0;
  if (!fb) {
    float hiT = S + eb, loT = S - eb;
    int kb = 0, bs0 = 0;
#pragma unroll
    for (int j = 0; j < 8; j++) {
      int e = lane + 64 * j;
      bool vj = (e < L);
      float v = ve[j];
      bool above = vj && (v > hiT);
      bool band = vj && !above && (v >= loT);
      unsigned long long ab = __ballot(above);
      int pa = kb + (int)__popcll(ab & ((1ull << lane) - 1ull));
      if (above && pa < 40) { keepV[pa] = v; keepI[pa] = ie[j]; }
      kb += (int)__popcll(ab);
      unsigned long long bbl = __ballot(band);
      int pb = bs0 + (int)__popcll(bbl & ((1ull << lane) - 1ull));
      if (band && pb < 96) bandU[pb] = make_uint2(__float_as_uint(v), (uint32_t)ie[j]);
      bs0 += (int)__popcll(bbl);
    }
    __syncthreads();
    int A = kb < 40 ? kb : 40;            // A <= 31 by rank invariant; clamp defensively
    int BC = bs0 < 96 ? bs0 : 96;
    int need = 32 - A;
    bool heavy = (BC > need);
    if (heavy) {
      // resolve band order with the bitwise round-1 fp32 chain
      for (int s = lane; s < BC; s += 64) {
        int m = (int)bandU[s].y & (Nn - 1);
        const float* xm = xbb + (size_t)m * Dd;
        float dot = 0.f;
        for (int k2 = 0; k2 < Dd; k2 += 4) {
          float4 a4 = *(const float4*)(xn + k2);
          float4 b4 = *(const float4*)(xm + k2);
          dot = fmaf(a4.x, b4.x, dot);
          dot = fmaf(a4.y, b4.y, dot);
          dot = fmaf(a4.z, b4.z, dot);
          dot = fmaf(a4.w, b4.w, dot);
        }
        bandRef[s] = (dot * ra) * rv[m];
      }
    }
    __syncthreads();
    if (lane == 0) {
      int kcl = A;
      if (!heavy) {
        for (int s = 0; s < BC && kcl < 40; s++) {
          keepV[kcl] = __uint_as_float(bandU[s].x);
          keepI[kcl] = (int)bandU[s].y;
          kcl++;
        }
      } else {
        for (int s = 0; s < need && kcl < 40; s++) {
          float bv = -1e30f; int bidx = 0x7FFFFFFF; int bsel = -1;
          for (int q = 0; q < BC; q++) {
            uint32_t gi = bandU[q].y;
            if (gi == 0xFFFFFFFFu) continue;
            float v = bandRef[q];
            if (v > bv || (v == bv && (int)gi < bidx)) { bv = v; bidx = (int)gi; bsel = q; }
          }
          if (bsel < 0) break;
          keepV[kcl] = __uint_as_float(bandU[bsel].x);
          keepI[kcl] = bidx;
          bandU[bsel].y = 0xFFFFFFFFu;
          kcl++;
        }
      }
      kcEnd = kcl;
    }
    __syncthreads();
    KC = kcEnd;
  } else {
    // safety path: fast-filter (independent 4-chain) then exact-chain re-rank
    if (lane == 0) wcnt = 0;
    __syncthreads();
    for (int c2 = lane; c2 < Nn; c2 += 64) {
      const float* xm = xbb + (size_t)c2 * Dd;
      float d0 = 0.f, d1 = 0.f, d2 = 0.f, d3 = 0.f;
      for (int k2 = 0; k2 < Dd; k2 += 4) {
        float4 a4 = *(const float4*)(xn + k2);
        float4 b4 = *(const float4*)(xm + k2);
        d0 = fmaf(a4.x, b4.x, d0); d1 = fmaf(a4.y, b4.y, d1);
        d2 = fmaf(a4.z, b4.z, d2); d3 = fmaf(a4.w, b4.w, d3);
      }
      float vf = (((d0 + d1) + (d2 + d3)) * ra) * rv[c2];
      if (vf > 0.07f) {   // v32 >= 0.095 over all rows: huge margin
        int pp = atomicAdd(&wcnt, 1);
        if (pp < 512) cl[pp] = make_uint2(0u, (uint32_t)c2);
      }
    }
    __syncthreads();
    int Lf = wcnt; if (Lf > 512) Lf = 512;
    // exact round-1 chain values for survivors
    for (int s = lane; s < Lf; s += 64) {
      int m = (int)cl[s].y & (Nn - 1);
      const float* xm = xbb + (size_t)m * Dd;
      float dot = 0.f;
      for (int k2 = 0; k2 < Dd; k2 += 4) {
        float4 a4 = *(const float4*)(xn + k2);
        float4 b4 = *(const float4*)(xm + k2);
        dot = fmaf(a4.x, b4.x, dot);
        dot = fmaf(a4.y, b4.y, dot);
        dot = fmaf(a4.z, b4.z, dot);
        dot = fmaf(a4.w, b4.w, dot);
      }
      cl[s].x = __float_as_uint((dot * ra) * rv[m]);
    }
    __syncthreads();
#pragma unroll
    for (int j = 0; j < 8; j++) {
      int e = lane + 64 * j;
      if (e < Lf) { uint2 u = cl[e]; ve[j] = __uint_as_float(u.x); ie[j] = (int)u.y; rk[j] = 0; }
      else { ve[j] = 0.f; ie[j] = 0; rk[j] = 1 << 20; }
    }
    for (int q = 0; q < Lf; q++) {
      uint2 u = cl[q];
      float vq = __uint_as_float(u.x); int iq = (int)u.y;
#pragma unroll
      for (int j = 0; j < 8; j++)
        rk[j] += ((vq > ve[j]) || (vq == ve[j] && iq < ie[j])) ? 1 : 0;
    }
    int kb = 0;
#pragma unroll
    for (int j = 0; j < 8; j++) {
      bool keep = (rk[j] < 32);
      unsigned long long kbm = __ballot(keep);
      int pk = kb + (int)__popcll(kbm & ((1ull << lane) - 1ull));
      if (keep && pk < 40) { keepV[pk] = ve[j]; keepI[pk] = ie[j]; }
      kb += (int)__popcll(kbm);
    }
    __syncthreads();
    KC = kb < 40 ? kb : 40;
  }

  if (lane < KC) {
    int m = keepI[lane] & (Nn - 1);
    float hv = 0.5f * keepV[lane];
    float* ob = out + (((size_t)bb) << 24);
    atomicAdd(ob + (size_t)rl * Nn + m, hv);
    atomicAdd(ob + (size_t)m * Nn + rl, hv);
  }
}

extern "C" void kernel_launch(void* const* d_in, const int* in_sizes, int n_in,
                              void* d_out, int out_size, void* d_ws, size_t ws_size,
                              hipStream_t stream) {
  const float* x = (const float*)d_in[0];
  float* out = (float*)d_out;
  // ws layout: rinv 64KB | xh 16MB | xl 16MB | simb 128MB
  float* rinv = (float*)d_ws;
  u16* xh = (u16*)((char*)d_ws + 65536);
  u16* xl = xh + (size_t)Bsz * Nn * Dd;
  u16* simb = xl + (size_t)Bsz * Nn * Dd;

  prep_kernel<<<Bsz * Nn, 128, 0, stream>>>(x, rinv, xh, xl, (float4*)out);
  dim3 g2(528, Bsz);
  gemm_sym<<<g2, 256, 0, stream>>>(xh, xl, simb);
  select_kernel<<<Bsz * Nn, 64, 0, stream>>>(simb, x, rinv, out);
}